// Round 4
// baseline (123.232 us; speedup 1.0000x reference)
//
#include <hip/hip_runtime.h>
#include <math.h>

#define B_ 4
#define T_ 512
#define C_ 128
#define HS_ 64

typedef float f4 __attribute__((ext_vector_type(4)));

// scale = C^-0.5
#define SCALE_ 0.08838834764831845f

// ---------------------------------------------------------------------------
// Kernel 1: prep.  x1 = x + pos_emb;  Aq = x1@W1q + b1;  Ak = x1@W1k; V = x@Wv
// 256 blocks x 640 threads (10 waves). Block = 8 rows.
// Thread: q = t>>3 (col-quad 0..79), r = t&7 (row). The 8 threads sharing a
// W column-quad are CONSECUTIVE LANES -> same W address in one wave-load ->
// TA dedupes -> W traffic 40MB total (was 327MB with q-major mapping).
// Branch regions are wave-aligned (q<32 <=> t<256, q<64 <=> t<512).
// ---------------------------------------------------------------------------
__global__ __launch_bounds__(640) void k_prep(
    const float* __restrict__ x, const float* __restrict__ pos,
    const float* __restrict__ W1, const float* __restrict__ b1,
    const float* __restrict__ Wv,
    float* __restrict__ Aq, float* __restrict__ Ak, float* __restrict__ V)
{
    __shared__ float x1s[8 * 132];   // pad 132: compute-read is 8 rows same c
    __shared__ float xs[8 * 132];    // -> distinct banks + broadcast
    const int t = threadIdx.x;
    const int row0 = blockIdx.x * 8;  // over B*T = 2048

    if (t < 256) {
        int r = t >> 5, cq = t & 31;
        int gr = row0 + r;
        f4 xv = *(const f4*)(x + gr * 128 + cq * 4);
        f4 pv = *(const f4*)(pos + (gr & 511) * 128 + cq * 4);
        *(f4*)&xs[r * 132 + cq * 4] = xv;
        *(f4*)&x1s[r * 132 + cq * 4] = xv + pv;
    }
    __syncthreads();

    const int q = t >> 3;   // 0..79 col-quad
    const int r = t & 7;    // row in tile

    const float* wbase;
    int wstr, col0;
    const float* xb;
    float* obase;
    int ostr;
    f4 binit = {0.f, 0.f, 0.f, 0.f};
    if (q < 32) {
        col0 = q * 4;
        wbase = W1 + 128 * 128 + col0;  // W1q rows (c-major)
        wstr = 128;
        xb = x1s;
        obase = Aq;
        ostr = 128;
        binit = *(const f4*)(b1 + col0);
    } else if (q < 64) {
        col0 = (q - 32) * 4;
        wbase = W1 + col0;  // W1k rows
        wstr = 128;
        xb = x1s;
        obase = Ak;
        ostr = 128;
    } else {
        col0 = (q - 64) * 4;
        wbase = Wv + col0;
        wstr = 64;
        xb = xs;
        obase = V;
        ostr = 64;
    }

    f4 acc = binit;
    const float* xr = xb + r * 132;
#pragma unroll 8
    for (int c = 0; c < 128; ++c) {
        f4 w = *(const f4*)(wbase + c * wstr);
        acc += xr[c] * w;
    }

    int gr = row0 + r;
    *(f4*)(obase + gr * ostr + col0) = acc;
}

// ---------------------------------------------------------------------------
// Kernel 2: fused wei + causal softmax + PV (flash-style). S never hits memory.
// Block = 4 query rows (QBLK=4) of one batch. 256 threads = 4 waves.
// Per j-tile of 32 keys:
//   S-compute: wave w covers j-slice [w*8, w*8+8); lane = j3*8+cs computes
//     all 4 rows over c-slice {u*32+cs*4 .. +4} (u=0..3) -> 192 VALU/lane.
//     ak read straight from L2, coalesced (no LDS staging). Reduce over cs
//     (shfl_xor 1,2,4), cs==0 lanes write sbuf[4][32] (double-buffered).
//   softmax: wave w owns row w; online max/sum (m,l) with rescale.
//   PV: lane = h; p broadcast from LDS; V rows from L2 (L1-cached, 4x reuse).
// b2 is a constant shift inside softmax -> dropped (exactly cancels).
// Blocks issued in DESCENDING i order: backfill balances the causal skew.
// ---------------------------------------------------------------------------
__global__ __launch_bounds__(256) void k_fused(
    const float* __restrict__ Aq, const float* __restrict__ Ak,
    const float* __restrict__ V, const float* __restrict__ W2,
    float* __restrict__ out)
{
    __shared__ float sbuf[2][4][32];
    __shared__ float pbuf[4][32];

    const int bx = blockIdx.x;        // 0..511
    const int b  = bx & 3;
    const int ig = 127 - (bx >> 2);   // descending i-group
    const int i0 = ig * 4;
    const int t = threadIdx.x;
    const int w = t >> 6;             // wave 0..3
    const int lane = t & 63;
    const int j3 = lane >> 3;         // 0..7
    const int cs = lane & 7;          // c-slice selector

    // hoist aq (4 rows x 16 c) and w2 (16 c); c = u*32 + cs*4
    f4 aqr[4][4], w2r[4];
#pragma unroll
    for (int u = 0; u < 4; ++u) {
        w2r[u] = *(const f4*)(W2 + u * 32 + cs * 4);
#pragma unroll
        for (int i = 0; i < 4; ++i)
            aqr[i][u] = *(const f4*)(Aq + (size_t)(b * T_ + i0 + i) * C_ + u * 32 + cs * 4);
    }

    float m = -1e30f, l = 0.f, acc = 0.f;
    const int jt_max = (i0 + 3) >> 5;
    const float* akb = Ak + (size_t)b * T_ * C_;
    const float* vb  = V + (size_t)b * T_ * HS_;
    const int irow = i0 + w;

    int pp = 0;
    for (int jt = 0; jt <= jt_max; ++jt, pp ^= 1) {
        // ---- S tile: rows i0..i0+3 x cols jt*32..+31 ----
        const int j = jt * 32 + w * 8 + j3;
        const float* akrow = akb + j * C_ + cs * 4;
        f4 kk[4];
#pragma unroll
        for (int u = 0; u < 4; ++u) kk[u] = *(const f4*)(akrow + u * 32);

        float sp[4];
#pragma unroll
        for (int i = 0; i < 4; ++i) {
            f4 a = {0.f, 0.f, 0.f, 0.f};
#pragma unroll
            for (int u = 0; u < 4; ++u) {
                f4 tt = aqr[i][u] + kk[u];
                tt.x = fmaxf(tt.x, 0.f);
                tt.y = fmaxf(tt.y, 0.f);
                tt.z = fmaxf(tt.z, 0.f);
                tt.w = fmaxf(tt.w, 0.f);
                a += tt * w2r[u];
            }
            float s = (a.x + a.y) + (a.z + a.w);
            s += __shfl_xor(s, 1);
            s += __shfl_xor(s, 2);
            s += __shfl_xor(s, 4);
            sp[i] = s;
        }
        if (cs == 0) {
#pragma unroll
            for (int i = 0; i < 4; ++i) sbuf[pp][i][w * 8 + j3] = sp[i];
        }
        __syncthreads();

        // ---- online softmax, wave w owns row irow ----
        float s = -1e30f;
        if (lane < 32) {
            int gj = jt * 32 + lane;
            if (gj <= irow) s = sbuf[pp][w][lane] * SCALE_;
        }
        float pm = s;
#pragma unroll
        for (int off = 1; off < 64; off <<= 1) pm = fmaxf(pm, __shfl_xor(pm, off));
        float mn = fmaxf(m, pm);
        float alpha = __expf(m - mn);
        float p = __expf(s - mn);           // masked/dead lanes -> 0
        if (lane < 32) pbuf[w][lane] = p;
        float ls = p;
#pragma unroll
        for (int off = 1; off < 64; off <<= 1) ls += __shfl_xor(ls, off);
        l = l * alpha + ls;
        m = mn;

        // ---- PV: acc[h] update, 4 independent chains ----
        const float* vt = vb + (size_t)(jt * 32) * HS_ + lane;
        float t0 = 0.f, t1 = 0.f, t2 = 0.f, t3 = 0.f;
#pragma unroll
        for (int jj = 0; jj < 32; jj += 4) {
            t0 += pbuf[w][jj]     * vt[(jj)     * HS_];
            t1 += pbuf[w][jj + 1] * vt[(jj + 1) * HS_];
            t2 += pbuf[w][jj + 2] * vt[(jj + 2) * HS_];
            t3 += pbuf[w][jj + 3] * vt[(jj + 3) * HS_];
        }
        acc = acc * alpha + ((t0 + t1) + (t2 + t3));
    }

    out[(size_t)(b * T_ + irow) * HS_ + lane] = acc / l;
}

// ---------------------------------------------------------------------------
extern "C" void kernel_launch(void* const* d_in, const int* in_sizes, int n_in,
                              void* d_out, int out_size, void* d_ws, size_t ws_size,
                              hipStream_t stream)
{
    const float* x   = (const float*)d_in[0];
    const float* pos = (const float*)d_in[1];
    const float* W1  = (const float*)d_in[2];
    const float* b1  = (const float*)d_in[3];
    const float* W2  = (const float*)d_in[4];
    const float* b2  = (const float*)d_in[5];  (void)b2;  // cancels in softmax
    const float* Wv  = (const float*)d_in[6];
    float* out = (float*)d_out;
    float* ws = (float*)d_ws;

    float* Aq = ws;                 // B*T*C = 262144
    float* Ak = ws + 262144;        // 262144
    float* V  = ws + 524288;        // B*T*HS = 131072

    k_prep<<<dim3(256), dim3(640), 0, stream>>>(x, pos, W1, b1, Wv, Aq, Ak, V);
    k_fused<<<dim3(512), dim3(256), 0, stream>>>(Aq, Ak, V, W2, out);
}

// Round 5
// 102.227 us; speedup vs baseline: 1.2055x; 1.2055x over previous
//
#include <hip/hip_runtime.h>
#include <math.h>

#define B_ 4
#define T_ 512
#define C_ 128
#define HS_ 64

typedef float f4 __attribute__((ext_vector_type(4)));

// scale = C^-0.5
#define SCALE_ 0.08838834764831845f

// ---------------------------------------------------------------------------
// Kernel 1: prep.  x1 = x + pos_emb;  Aq = x1@W1q + b1;  Ak = x1@W1k; V = x@Wv
// 256 blocks x 640 threads (10 waves). Block = 8 rows.
// Thread: q = t>>3 (col-quad 0..79), r = t&7 (row). The 8 threads sharing a
// W column-quad are CONSECUTIVE LANES -> one broadcast W load per octet.
// ---------------------------------------------------------------------------
__global__ __launch_bounds__(640) void k_prep(
    const float* __restrict__ x, const float* __restrict__ pos,
    const float* __restrict__ W1, const float* __restrict__ b1,
    const float* __restrict__ Wv,
    float* __restrict__ Aq, float* __restrict__ Ak, float* __restrict__ V)
{
    __shared__ float x1s[8 * 132];
    __shared__ float xs[8 * 132];
    const int t = threadIdx.x;
    const int row0 = blockIdx.x * 8;  // over B*T = 2048

    if (t < 256) {
        int r = t >> 5, cq = t & 31;
        int gr = row0 + r;
        f4 xv = *(const f4*)(x + gr * 128 + cq * 4);
        f4 pv = *(const f4*)(pos + (gr & 511) * 128 + cq * 4);
        *(f4*)&xs[r * 132 + cq * 4] = xv;
        *(f4*)&x1s[r * 132 + cq * 4] = xv + pv;
    }
    __syncthreads();

    const int q = t >> 3;   // 0..79 col-quad
    const int r = t & 7;    // row in tile

    const float* wbase;
    int wstr, col0;
    const float* xb;
    float* obase;
    int ostr;
    f4 binit = {0.f, 0.f, 0.f, 0.f};
    if (q < 32) {
        col0 = q * 4;
        wbase = W1 + 128 * 128 + col0;  // W1q rows (c-major)
        wstr = 128;
        xb = x1s;
        obase = Aq;
        ostr = 128;
        binit = *(const f4*)(b1 + col0);
    } else if (q < 64) {
        col0 = (q - 32) * 4;
        wbase = W1 + col0;  // W1k rows
        wstr = 128;
        xb = x1s;
        obase = Ak;
        ostr = 128;
    } else {
        col0 = (q - 64) * 4;
        wbase = Wv + col0;
        wstr = 64;
        xb = xs;
        obase = V;
        ostr = 64;
    }

    f4 acc = binit;
    const float* xr = xb + r * 132;
#pragma unroll 8
    for (int c = 0; c < 128; ++c) {
        f4 w = *(const f4*)(wbase + c * wstr);
        acc += xr[c] * w;
    }

    int gr = row0 + r;
    *(f4*)(obase + gr * ostr + col0) = acc;
}

// ---------------------------------------------------------------------------
// Kernel 2: fused wei + causal softmax + PV — barrier-free per-wave flash.
// Block = 256 thr = 4 waves = 2 adjacent query rows x 2 j-splits.
// Wave (row, split) loops jt = split, split+2, ... <= row>>5 independently:
// NO __syncthreads in the loop. Lane = (j2 = lane>>1, half = lane&1):
//   S: lane sums relu(Aq[row,c]+Ak[j,c])*W2[c] over its 64-c half
//      (Aq hoisted to 16 f4 regs; W2 from LDS, broadcast), then
//      shfl_xor(1) pair-combine -> S[j] in both pair lanes.
//   online softmax: 5-shfl tile max, 6-shfl sum (pair-dup summed, x0.5).
//   PV: p via per-wave LDS broadcast (within-wave, no barrier); V rows
//      coalesced; acc[h=lane] with 4 chains.
// End: split-merge via LDS + one barrier; even wave writes out.
// b2 cancels in softmax. Heavy blocks (large i) dispatched first.
// ---------------------------------------------------------------------------
__global__ __launch_bounds__(256) void k_fused(
    const float* __restrict__ Aq, const float* __restrict__ Ak,
    const float* __restrict__ V, const float* __restrict__ W2,
    float* __restrict__ out)
{
    __shared__ float w2s[128];
    __shared__ float pbuf[4][32];
    __shared__ float mls[4][2];
    __shared__ float accs[4][64];

    const int t = threadIdx.x;
    const int w = t >> 6;
    const int lane = t & 63;
    const int bx = blockIdx.x;            // 0..1023
    const int b = bx & 3;
    const int g = 255 - (bx >> 2);        // descending row-pair
    const int row = g * 2 + (w >> 1);
    const int split = w & 1;

    if (t < 32) *(f4*)&w2s[t * 4] = *(const f4*)(W2 + t * 4);
    __syncthreads();

    const int j2 = lane >> 1;
    const int half = lane & 1;

    // hoist Aq row half: 16 f4
    const float* aqrow = Aq + (size_t)(b * T_ + row) * C_ + half * 64;
    f4 aqr[16];
#pragma unroll
    for (int u = 0; u < 16; ++u) aqr[u] = *(const f4*)(aqrow + u * 4);

    const float* w2h = &w2s[half * 64];
    const float* akb = Ak + (size_t)b * T_ * C_;
    const float* vb  = V + (size_t)b * T_ * HS_;

    float m = -1e30f, l = 0.f, acc = 0.f;
    const int jtm = row >> 5;

    for (int jt = split; jt <= jtm; jt += 2) {
        // ---- S for j = jt*32 + j2 over this lane's c-half ----
        const float* akrow = akb + (size_t)(jt * 32 + j2) * C_ + half * 64;
        f4 a4 = {0.f, 0.f, 0.f, 0.f};
#pragma unroll 8
        for (int u = 0; u < 16; ++u) {
            f4 kk = *(const f4*)(akrow + u * 4);
            f4 wv = *(const f4*)(w2h + u * 4);
            f4 tt = aqr[u] + kk;
            tt.x = fmaxf(tt.x, 0.f);
            tt.y = fmaxf(tt.y, 0.f);
            tt.z = fmaxf(tt.z, 0.f);
            tt.w = fmaxf(tt.w, 0.f);
            a4 += tt * wv;
        }
        float s = (a4.x + a4.y) + (a4.z + a4.w);
        s += __shfl_xor(s, 1);            // combine halves -> full-c dot
        s *= SCALE_;
        const int gj = jt * 32 + j2;
        if (gj > row) s = -1e30f;         // causal mask

        // ---- online softmax (within wave) ----
        float tm = s;
#pragma unroll
        for (int off = 2; off < 64; off <<= 1) tm = fmaxf(tm, __shfl_xor(tm, off));
        const float mn = fmaxf(m, tm);
        const float alpha = __expf(m - mn);
        const float p = __expf(s - mn);   // masked -> 0
        if (!half) pbuf[w][j2] = p;       // within-wave visible (lgkmcnt)
        float ls = p;
#pragma unroll
        for (int off = 1; off < 64; off <<= 1) ls += __shfl_xor(ls, off);
        l = l * alpha + 0.5f * ls;        // pair-duplicated sum
        m = mn;

        // ---- PV: acc[h=lane] ----
        const float* vt = vb + (size_t)(jt * 32) * HS_ + lane;
        float t0 = 0.f, t1 = 0.f, t2 = 0.f, t3 = 0.f;
#pragma unroll
        for (int jj = 0; jj < 32; jj += 4) {
            t0 += pbuf[w][jj]     * vt[(jj)     * HS_];
            t1 += pbuf[w][jj + 1] * vt[(jj + 1) * HS_];
            t2 += pbuf[w][jj + 2] * vt[(jj + 2) * HS_];
            t3 += pbuf[w][jj + 3] * vt[(jj + 3) * HS_];
        }
        acc = acc * alpha + ((t0 + t1) + (t2 + t3));
    }

    // ---- split merge ----
    if (lane == 0) { mls[w][0] = m; mls[w][1] = l; }
    accs[w][lane] = acc;
    __syncthreads();

    if (!(w & 1)) {
        const float m1 = mls[w + 1][0], l1 = mls[w + 1][1];
        const float a1 = accs[w + 1][lane];
        const float ms = fmaxf(m, m1);
        const float e0 = __expf(m - ms), e1 = __expf(m1 - ms);
        const float num = acc * e0 + a1 * e1;
        const float den = l * e0 + l1 * e1;
        out[(size_t)(b * T_ + row) * HS_ + lane] = num / den;
    }
}

// ---------------------------------------------------------------------------
extern "C" void kernel_launch(void* const* d_in, const int* in_sizes, int n_in,
                              void* d_out, int out_size, void* d_ws, size_t ws_size,
                              hipStream_t stream)
{
    const float* x   = (const float*)d_in[0];
    const float* pos = (const float*)d_in[1];
    const float* W1  = (const float*)d_in[2];
    const float* b1  = (const float*)d_in[3];
    const float* W2  = (const float*)d_in[4];
    const float* b2  = (const float*)d_in[5];  (void)b2;  // cancels in softmax
    const float* Wv  = (const float*)d_in[6];
    float* out = (float*)d_out;
    float* ws = (float*)d_ws;

    float* Aq = ws;                 // B*T*C = 262144
    float* Ak = ws + 262144;        // 262144
    float* V  = ws + 524288;        // B*T*HS = 131072

    k_prep<<<dim3(256), dim3(640), 0, stream>>>(x, pos, W1, b1, Wv, Aq, Ak, V);
    k_fused<<<dim3(1024), dim3(256), 0, stream>>>(Aq, Ak, V, W2, out);
}

// Round 6
// 102.207 us; speedup vs baseline: 1.2057x; 1.0002x over previous
//
#include <hip/hip_runtime.h>
#include <math.h>

#define B_ 4
#define T_ 512
#define C_ 128
#define HS_ 64

typedef float f4 __attribute__((ext_vector_type(4)));

// scale = C^-0.5
#define SCALE_ 0.08838834764831845f

// ---------------------------------------------------------------------------
// Kernel 1: prep.  x1 = x + pos_emb;  Aq = x1@W1q + b1;  Ak = x1@W1k; V = x@Wv
// 256 blocks x 640 threads (10 waves). Block = 8 rows.
// Thread: q = t>>3 (col-quad 0..79), r = t&7 (row). The 8 threads sharing a
// W column-quad are CONSECUTIVE LANES -> one broadcast W load per octet.
// ---------------------------------------------------------------------------
__global__ __launch_bounds__(640) void k_prep(
    const float* __restrict__ x, const float* __restrict__ pos,
    const float* __restrict__ W1, const float* __restrict__ b1,
    const float* __restrict__ Wv,
    float* __restrict__ Aq, float* __restrict__ Ak, float* __restrict__ V)
{
    __shared__ float x1s[8 * 132];
    __shared__ float xs[8 * 132];
    const int t = threadIdx.x;
    const int row0 = blockIdx.x * 8;  // over B*T = 2048

    if (t < 256) {
        int r = t >> 5, cq = t & 31;
        int gr = row0 + r;
        f4 xv = *(const f4*)(x + gr * 128 + cq * 4);
        f4 pv = *(const f4*)(pos + (gr & 511) * 128 + cq * 4);
        *(f4*)&xs[r * 132 + cq * 4] = xv;
        *(f4*)&x1s[r * 132 + cq * 4] = xv + pv;
    }
    __syncthreads();

    const int q = t >> 3;   // 0..79 col-quad
    const int r = t & 7;    // row in tile

    const float* wbase;
    int wstr, col0;
    const float* xb;
    float* obase;
    int ostr;
    f4 binit = {0.f, 0.f, 0.f, 0.f};
    if (q < 32) {
        col0 = q * 4;
        wbase = W1 + 128 * 128 + col0;  // W1q rows (c-major)
        wstr = 128;
        xb = x1s;
        obase = Aq;
        ostr = 128;
        binit = *(const f4*)(b1 + col0);
    } else if (q < 64) {
        col0 = (q - 32) * 4;
        wbase = W1 + col0;  // W1k rows
        wstr = 128;
        xb = x1s;
        obase = Ak;
        ostr = 128;
    } else {
        col0 = (q - 64) * 4;
        wbase = Wv + col0;
        wstr = 64;
        xb = xs;
        obase = V;
        ostr = 64;
    }

    f4 acc = binit;
    const float* xr = xb + r * 132;
#pragma unroll 8
    for (int c = 0; c < 128; ++c) {
        f4 w = *(const f4*)(wbase + c * wstr);
        acc += xr[c] * w;
    }

    int gr = row0 + r;
    *(f4*)(obase + gr * ostr + col0) = acc;
}

// ---------------------------------------------------------------------------
// Kernel 2: fused wei + causal softmax + PV — barrier-free per-wave flash.
// Block = 256 thr = 4 waves = 2 adjacent query rows x 2 j-splits.
// Wave (row, split) loops jt = split, split+2, ... <= row>>5 independently:
// NO __syncthreads in the loop.
// __launch_bounds__(256, 3): 3 waves/EU -> VGPR cap ~170. Round-5's default
// cap was 48 VGPR -> aqr[16] spilled to scratch -> 173 MB/dispatch of
// scratch traffic at 1.95 TB/s = the whole 90 us. The hoist needs ~110 VGPR.
// ---------------------------------------------------------------------------
__global__ __launch_bounds__(256, 3) void k_fused(
    const float* __restrict__ Aq, const float* __restrict__ Ak,
    const float* __restrict__ V, const float* __restrict__ W2,
    float* __restrict__ out)
{
    __shared__ float w2s[128];
    __shared__ float pbuf[4][32];
    __shared__ float mls[4][2];
    __shared__ float accs[4][64];

    const int t = threadIdx.x;
    const int w = t >> 6;
    const int lane = t & 63;
    const int bx = blockIdx.x;            // 0..1023
    const int b = bx & 3;
    const int g = 255 - (bx >> 2);        // descending row-pair
    const int row = g * 2 + (w >> 1);
    const int split = w & 1;

    if (t < 32) *(f4*)&w2s[t * 4] = *(const f4*)(W2 + t * 4);
    __syncthreads();

    const int j2 = lane >> 1;
    const int half = lane & 1;

    // hoist Aq row half: 16 f4 (64 VGPR — the reason for launch_bounds(,3))
    const float* aqrow = Aq + (size_t)(b * T_ + row) * C_ + half * 64;
    f4 aqr[16];
#pragma unroll
    for (int u = 0; u < 16; ++u) aqr[u] = *(const f4*)(aqrow + u * 4);

    const float* w2h = &w2s[half * 64];
    const float* akb = Ak + (size_t)b * T_ * C_;
    const float* vb  = V + (size_t)b * T_ * HS_;

    float m = -1e30f, l = 0.f, acc = 0.f;
    const int jtm = row >> 5;

    for (int jt = split; jt <= jtm; jt += 2) {
        // ---- S for j = jt*32 + j2 over this lane's c-half ----
        const float* akrow = akb + (size_t)(jt * 32 + j2) * C_ + half * 64;
        f4 a4 = {0.f, 0.f, 0.f, 0.f};
#pragma unroll 8
        for (int u = 0; u < 16; ++u) {
            f4 kk = *(const f4*)(akrow + u * 4);
            f4 wv = *(const f4*)(w2h + u * 4);
            f4 tt = aqr[u] + kk;
            tt.x = fmaxf(tt.x, 0.f);
            tt.y = fmaxf(tt.y, 0.f);
            tt.z = fmaxf(tt.z, 0.f);
            tt.w = fmaxf(tt.w, 0.f);
            a4 += tt * wv;
        }
        float s = (a4.x + a4.y) + (a4.z + a4.w);
        s += __shfl_xor(s, 1);            // combine halves -> full-c dot
        s *= SCALE_;
        const int gj = jt * 32 + j2;
        if (gj > row) s = -1e30f;         // causal mask

        // ---- online softmax (within wave) ----
        float tm = s;
#pragma unroll
        for (int off = 2; off < 64; off <<= 1) tm = fmaxf(tm, __shfl_xor(tm, off));
        const float mn = fmaxf(m, tm);
        const float alpha = __expf(m - mn);
        const float p = __expf(s - mn);   // masked -> 0
        if (!half) pbuf[w][j2] = p;       // within-wave visible (lgkmcnt)
        float ls = p;
#pragma unroll
        for (int off = 1; off < 64; off <<= 1) ls += __shfl_xor(ls, off);
        l = l * alpha + 0.5f * ls;        // pair-duplicated sum
        m = mn;

        // ---- PV: acc[h=lane] ----
        const float* vt = vb + (size_t)(jt * 32) * HS_ + lane;
        float t0 = 0.f, t1 = 0.f, t2 = 0.f, t3 = 0.f;
#pragma unroll
        for (int jj = 0; jj < 32; jj += 4) {
            t0 += pbuf[w][jj]     * vt[(jj)     * HS_];
            t1 += pbuf[w][jj + 1] * vt[(jj + 1) * HS_];
            t2 += pbuf[w][jj + 2] * vt[(jj + 2) * HS_];
            t3 += pbuf[w][jj + 3] * vt[(jj + 3) * HS_];
        }
        acc = acc * alpha + ((t0 + t1) + (t2 + t3));
    }

    // ---- split merge ----
    if (lane == 0) { mls[w][0] = m; mls[w][1] = l; }
    accs[w][lane] = acc;
    __syncthreads();

    if (!(w & 1)) {
        const float m1 = mls[w + 1][0], l1 = mls[w + 1][1];
        const float a1 = accs[w + 1][lane];
        const float ms = fmaxf(m, m1);
        const float e0 = __expf(m - ms), e1 = __expf(m1 - ms);
        const float num = acc * e0 + a1 * e1;
        const float den = l * e0 + l1 * e1;
        out[(size_t)(b * T_ + row) * HS_ + lane] = num / den;
    }
}

// ---------------------------------------------------------------------------
extern "C" void kernel_launch(void* const* d_in, const int* in_sizes, int n_in,
                              void* d_out, int out_size, void* d_ws, size_t ws_size,
                              hipStream_t stream)
{
    const float* x   = (const float*)d_in[0];
    const float* pos = (const float*)d_in[1];
    const float* W1  = (const float*)d_in[2];
    const float* b1  = (const float*)d_in[3];
    const float* W2  = (const float*)d_in[4];
    const float* b2  = (const float*)d_in[5];  (void)b2;  // cancels in softmax
    const float* Wv  = (const float*)d_in[6];
    float* out = (float*)d_out;
    float* ws = (float*)d_ws;

    float* Aq = ws;                 // B*T*C = 262144
    float* Ak = ws + 262144;        // 262144
    float* V  = ws + 524288;        // B*T*HS = 131072

    k_prep<<<dim3(256), dim3(640), 0, stream>>>(x, pos, W1, b1, Wv, Aq, Ak, V);
    k_fused<<<dim3(1024), dim3(256), 0, stream>>>(Aq, Ak, V, W2, out);
}

// Round 7
// 81.903 us; speedup vs baseline: 1.5046x; 1.2479x over previous
//
#include <hip/hip_runtime.h>
#include <math.h>

#define B_ 4
#define T_ 512
#define C_ 128
#define HS_ 64

typedef float f4 __attribute__((ext_vector_type(4)));

// scale = C^-0.5
#define SCALE_ 0.08838834764831845f

// ---------------------------------------------------------------------------
// Kernel 1: prep.  x1 = x + pos_emb;  Aq = x1@W1q + b1;  Ak = x1@W1k; V = x@Wv
// 256 blocks x 640 threads (10 waves). Block = 8 rows.
// Thread: q = t>>3 (col-quad 0..79), r = t&7 (row). The 8 threads sharing a
// W column-quad are CONSECUTIVE LANES -> one broadcast W load per octet.
// ---------------------------------------------------------------------------
__global__ __launch_bounds__(640) void k_prep(
    const float* __restrict__ x, const float* __restrict__ pos,
    const float* __restrict__ W1, const float* __restrict__ b1,
    const float* __restrict__ Wv,
    float* __restrict__ Aq, float* __restrict__ Ak, float* __restrict__ V)
{
    __shared__ float x1s[8 * 132];
    __shared__ float xs[8 * 132];
    const int t = threadIdx.x;
    const int row0 = blockIdx.x * 8;  // over B*T = 2048

    if (t < 256) {
        int r = t >> 5, cq = t & 31;
        int gr = row0 + r;
        f4 xv = *(const f4*)(x + gr * 128 + cq * 4);
        f4 pv = *(const f4*)(pos + (gr & 511) * 128 + cq * 4);
        *(f4*)&xs[r * 132 + cq * 4] = xv;
        *(f4*)&x1s[r * 132 + cq * 4] = xv + pv;
    }
    __syncthreads();

    const int q = t >> 3;   // 0..79 col-quad
    const int r = t & 7;    // row in tile

    const float* wbase;
    int wstr, col0;
    const float* xb;
    float* obase;
    int ostr;
    f4 binit = {0.f, 0.f, 0.f, 0.f};
    if (q < 32) {
        col0 = q * 4;
        wbase = W1 + 128 * 128 + col0;  // W1q rows (c-major)
        wstr = 128;
        xb = x1s;
        obase = Aq;
        ostr = 128;
        binit = *(const f4*)(b1 + col0);
    } else if (q < 64) {
        col0 = (q - 32) * 4;
        wbase = W1 + col0;  // W1k rows
        wstr = 128;
        xb = x1s;
        obase = Ak;
        ostr = 128;
    } else {
        col0 = (q - 64) * 4;
        wbase = Wv + col0;
        wstr = 64;
        xb = xs;
        obase = V;
        ostr = 64;
    }

    f4 acc = binit;
    const float* xr = xb + r * 132;
#pragma unroll 8
    for (int c = 0; c < 128; ++c) {
        f4 w = *(const f4*)(wbase + c * wstr);
        acc += xr[c] * w;
    }

    int gr = row0 + r;
    *(f4*)(obase + gr * ostr + col0) = acc;
}

// ---------------------------------------------------------------------------
// Kernel 2: fused wei + causal softmax + PV — barrier-free per-wave flash.
// Block = 256 thr = 4 waves = 2 adjacent query rows x 2 j-splits.
// Wave (row, split) loops jt = split, split+2, ... <= row>>5 independently:
// NO __syncthreads in the loop.
//
// CRITICAL (rule #20): the S-compute loop over u MUST be FULLY unrolled.
// Rounds 5-6 used "#pragma unroll 8" -> residual 2-iter loop with runtime u
// -> aqr[u] dynamically indexed -> compiler allocated aqr in SCRATCH
// (VGPR_Count=48, 107MB fetch + 66MB write of spill traffic, 91us).
// Full unroll keeps every aqr index compile-time -> register-resident.
// ---------------------------------------------------------------------------
__global__ __launch_bounds__(256, 3) void k_fused(
    const float* __restrict__ Aq, const float* __restrict__ Ak,
    const float* __restrict__ V, const float* __restrict__ W2,
    float* __restrict__ out)
{
    __shared__ float w2s[128];
    __shared__ float pbuf[4][32];
    __shared__ float mls[4][2];
    __shared__ float accs[4][64];

    const int t = threadIdx.x;
    const int w = t >> 6;
    const int lane = t & 63;
    const int bx = blockIdx.x;            // 0..1023
    const int b = bx & 3;
    const int g = 255 - (bx >> 2);        // descending row-pair
    const int row = g * 2 + (w >> 1);
    const int split = w & 1;

    if (t < 32) *(f4*)&w2s[t * 4] = *(const f4*)(W2 + t * 4);
    __syncthreads();

    const int j2 = lane >> 1;
    const int half = lane & 1;

    // hoist Aq row half: 16 f4 = 64 VGPRs (register-resident, see note above)
    const float* aqrow = Aq + (size_t)(b * T_ + row) * C_ + half * 64;
    f4 aqr[16];
#pragma unroll
    for (int u = 0; u < 16; ++u) aqr[u] = *(const f4*)(aqrow + u * 4);

    const float* w2h = &w2s[half * 64];
    const float* akb = Ak + (size_t)b * T_ * C_;
    const float* vb  = V + (size_t)b * T_ * HS_;

    float m = -1e30f, l = 0.f, acc = 0.f;
    const int jtm = row >> 5;

    for (int jt = split; jt <= jtm; jt += 2) {
        // ---- S for j = jt*32 + j2 over this lane's c-half ----
        const float* akrow = akb + (size_t)(jt * 32 + j2) * C_ + half * 64;
        f4 a4 = {0.f, 0.f, 0.f, 0.f};
#pragma unroll
        for (int u = 0; u < 16; ++u) {
            f4 kk = *(const f4*)(akrow + u * 4);
            f4 wv = *(const f4*)(w2h + u * 4);
            f4 tt = aqr[u] + kk;
            tt.x = fmaxf(tt.x, 0.f);
            tt.y = fmaxf(tt.y, 0.f);
            tt.z = fmaxf(tt.z, 0.f);
            tt.w = fmaxf(tt.w, 0.f);
            a4 += tt * wv;
        }
        float s = (a4.x + a4.y) + (a4.z + a4.w);
        s += __shfl_xor(s, 1);            // combine halves -> full-c dot
        s *= SCALE_;
        const int gj = jt * 32 + j2;
        if (gj > row) s = -1e30f;         // causal mask

        // ---- online softmax (within wave) ----
        float tm = s;
#pragma unroll
        for (int off = 2; off < 64; off <<= 1) tm = fmaxf(tm, __shfl_xor(tm, off));
        const float mn = fmaxf(m, tm);
        const float alpha = __expf(m - mn);
        const float p = __expf(s - mn);   // masked -> 0
        if (!half) pbuf[w][j2] = p;       // within-wave visible (lgkmcnt)
        float ls = p;
#pragma unroll
        for (int off = 1; off < 64; off <<= 1) ls += __shfl_xor(ls, off);
        l = l * alpha + 0.5f * ls;        // pair-duplicated sum
        m = mn;

        // ---- PV: acc[h=lane] ----
        const float* vt = vb + (size_t)(jt * 32) * HS_ + lane;
        float t0 = 0.f, t1 = 0.f, t2 = 0.f, t3 = 0.f;
#pragma unroll
        for (int jj = 0; jj < 32; jj += 4) {
            t0 += pbuf[w][jj]     * vt[(jj)     * HS_];
            t1 += pbuf[w][jj + 1] * vt[(jj + 1) * HS_];
            t2 += pbuf[w][jj + 2] * vt[(jj + 2) * HS_];
            t3 += pbuf[w][jj + 3] * vt[(jj + 3) * HS_];
        }
        acc = acc * alpha + ((t0 + t1) + (t2 + t3));
    }

    // ---- split merge ----
    if (lane == 0) { mls[w][0] = m; mls[w][1] = l; }
    accs[w][lane] = acc;
    __syncthreads();

    if (!(w & 1)) {
        const float m1 = mls[w + 1][0], l1 = mls[w + 1][1];
        const float a1 = accs[w + 1][lane];
        const float ms = fmaxf(m, m1);
        const float e0 = __expf(m - ms), e1 = __expf(m1 - ms);
        const float num = acc * e0 + a1 * e1;
        const float den = l * e0 + l1 * e1;
        out[(size_t)(b * T_ + row) * HS_ + lane] = num / den;
    }
}

// ---------------------------------------------------------------------------
extern "C" void kernel_launch(void* const* d_in, const int* in_sizes, int n_in,
                              void* d_out, int out_size, void* d_ws, size_t ws_size,
                              hipStream_t stream)
{
    const float* x   = (const float*)d_in[0];
    const float* pos = (const float*)d_in[1];
    const float* W1  = (const float*)d_in[2];
    const float* b1  = (const float*)d_in[3];
    const float* W2  = (const float*)d_in[4];
    const float* b2  = (const float*)d_in[5];  (void)b2;  // cancels in softmax
    const float* Wv  = (const float*)d_in[6];
    float* out = (float*)d_out;
    float* ws = (float*)d_ws;

    float* Aq = ws;                 // B*T*C = 262144
    float* Ak = ws + 262144;        // 262144
    float* V  = ws + 524288;        // B*T*HS = 131072

    k_prep<<<dim3(256), dim3(640), 0, stream>>>(x, pos, W1, b1, Wv, Aq, Ak, V);
    k_fused<<<dim3(1024), dim3(256), 0, stream>>>(Aq, Ak, V, W2, out);
}